// Round 9
// baseline (93.651 us; speedup 1.0000x reference)
//
#include <hip/hip_runtime.h>
#include <hip/hip_bf16.h>

// Problem constants: B=128, C=21, L=2048, W=32, S=8, O=16, NW=252, NK=4032, K=672
#define Bb   128
#define Cc   21
#define Ll   2048
#define Ss   8
#define Oo   16
#define NWw  252
#define NKk  4032
#define Kk   672
#define KP   680   // LDS pitch (bf16): 85 x 16B granules/row, conflict-light b128

typedef __attribute__((ext_vector_type(8))) short  short8;  // 8 bf16 = 4 VGPRs
typedef __attribute__((ext_vector_type(4))) float  f32x4;

static __device__ __forceinline__ unsigned short f2bf(float f) {
    union { __hip_bfloat16 h; unsigned short u; } cv;
    cv.h = __float2bfloat16(f);
    return cv.u;
}

static __device__ __forceinline__ short8 cvt8(const float4 a0, const float4 a1) {
    short8 a;
    a[0] = (short)f2bf(a0.x); a[1] = (short)f2bf(a0.y);
    a[2] = (short)f2bf(a0.z); a[3] = (short)f2bf(a0.w);
    a[4] = (short)f2bf(a1.x); a[5] = (short)f2bf(a1.y);
    a[6] = (short)f2bf(a1.z); a[7] = (short)f2bf(a1.w);
    return a;
}

// ---- Pass 1: XCD-matched L2 warm sweep of x. ----
// The harness's 256 MB ws-poison (== L3 size) sweeps L2+L3 right before us,
// so fb's 128-B-chunk reads at 8/172-KB strides are all cold HBM misses in
// row-buffer-hostile order -> chip read BW caps ~1.7 TB/s (R1/R4 profiles).
// Fix: XCD r (=bid%8, same mapping as fb) streams its column slab
// [256r, 256r+280) of every (b,c) row in long sequential runs -> slab
// (3.1 MB) lands in that XCD's 4 MB L2; fb then runs on L2 hits.
// Dummy per-thread sum stored to d_ws prevents DCE.
__global__ __launch_bounds__(256)
void l2warm(const float* __restrict__ x, float* __restrict__ wsf) {
    const int bid = blockIdx.x;
    const int r   = bid & 7;                 // XCD id (same heuristic as fb)
    const int t   = bid >> 3;                // 0..31 within XCD
    const int c0  = r * 256;                 // slab start column
    const int row0 = t * 84;                 // 2688 (b,c) rows / 32 blocks
    float acc = 0.f;
    for (int i = threadIdx.x; i < 84 * 70; i += 256) {   // 70 float4 = 280 cols
        int rw = i / 70;                      // const-div -> magic mul
        int c4 = i - rw * 70;
        int col = c0 + c4 * 4;
        if (col > Ll - 4) col = Ll - 4;       // clamp (r=7 slab ends at 2048)
        const float4 v = *(const float4*)(x + (size_t)(row0 + rw) * Ll + col);
        acc += v.x + v.y + v.z + v.w;
    }
    wsf[bid * 256 + threadIdx.x] = acc;       // DCE guard (ws scratch)
}

// ---- Pass 2: R8's kernel, unchanged (best so far). ----
// Grid 256 (252 windows + 4 idle), XCD r=bid%8 owns windows [32r,32r+32).
// 512 thr = 8 waves x 16-batch m-tiles = all 128 batches; w staged once per
// window fp32->bf16 into LDS; A-slice batch-issued then cvt'd in-register;
// one barrier; 21-MFMA sweep; direct fp32 C-write.
__global__ __launch_bounds__(512)
void fb_fwd(const float* __restrict__ x, const float* __restrict__ w,
            float* __restrict__ out) {
    __shared__ unsigned short ws[Oo * KP];   // 21.8 KB

    const int bid = blockIdx.x;
    const int j   = (bid & 7) * 32 + (bid >> 3);          // XCD-grouped window
    if (j >= NWw) return;                                  // 4 tail blocks idle
    const int s    = (j < NWw - 1) ? j * Ss : (Ll - 32);  // STARTS[j], mult of 8
    const int tid  = threadIdx.x;
    const int lane = tid & 63;
    const int wv   = tid >> 6;       // 0..7: m-tile id (16 batch rows)
    const int col  = lane & 15;      // MFMA m-row (A) / n-col (B = w-row o)
    const int quad = lane >> 4;      // k-chunk selector

    // batch-issue the whole A-slice (21 x 32 B fp32, all in flight)
    const float* xrow = x + ((size_t)(wv * 16 + col) * Cc) * Ll + s + quad * 8;
    float4 a0[Cc], a1[Cc];
#pragma unroll
    for (int c = 0; c < Cc; ++c) {
        a0[c] = *(const float4*)(xrow + (size_t)c * Ll);
        a1[c] = *(const float4*)(xrow + (size_t)c * Ll + 4);
    }

    // stage weight[j]: 16 x 672 fp32 -> bf16 LDS, [o][k] (B^T)
    {
        const float4* wj4 = (const float4*)(w + (size_t)j * Oo * Kk);
        for (int t = tid; t < Oo * (Kk / 4); t += 512) {   // 2688 float4
            float4 v = wj4[t];
            int o = t / (Kk / 4);                           // Kk/4 = 168
            int r = t - o * (Kk / 4);
            *(ushort4*)&ws[o * KP + r * 4] =
                make_ushort4(f2bf(v.x), f2bf(v.y), f2bf(v.z), f2bf(v.w));
        }
    }

    // cvt A to bf16 frags while the stage drains
    short8 afr[Cc];
#pragma unroll
    for (int c = 0; c < Cc; ++c) afr[c] = cvt8(a0[c], a1[c]);

    __syncthreads();

    const unsigned short* wrow = &ws[col * KP + quad * 8];
    f32x4 acc = {0.f, 0.f, 0.f, 0.f};
#pragma unroll
    for (int c = 0; c < Cc; ++c)
        acc = __builtin_amdgcn_mfma_f32_16x16x32_bf16(
            afr[c], *(const short8*)(wrow + c * 32), acc, 0, 0, 0);

    // C/D layout: col = lane&15, row = quad*4 + reg
    const int rbase = wv * 16 + quad * 4;
    float* op = out + (size_t)rbase * NKk + j * 16 + col;
#pragma unroll
    for (int r = 0; r < 4; ++r)
        op[(size_t)r * NKk] = acc[r];
}

extern "C" void kernel_launch(void* const* d_in, const int* in_sizes, int n_in,
                              void* d_out, int out_size, void* d_ws, size_t ws_size,
                              hipStream_t stream) {
    const float* x = (const float*)d_in[0];   // (128, 21, 2048) fp32
    const float* w = (const float*)d_in[1];   // (4032, 672) fp32
    float* out = (float*)d_out;               // (128, 4032) fp32
    l2warm<<<dim3(256), dim3(256), 0, stream>>>(x, (float*)d_ws);
    fb_fwd<<<dim3(256), dim3(512), 0, stream>>>(x, w, out);
}

// Round 10
// 86.373 us; speedup vs baseline: 1.0843x; 1.0843x over previous
//
#include <hip/hip_runtime.h>
#include <hip/hip_bf16.h>

// Problem constants: B=128, C=21, L=2048, W=32, S=8, O=16, NW=252, NK=4032, K=672
#define Bb   128
#define Cc   21
#define Ll   2048
#define Ss   8
#define Oo   16
#define NWw  252
#define NKk  4032
#define Kk   672
#define KP   680   // LDS pitch (bf16) for weight tile
#define NR   (Bb * Cc)        // 2688 (b,c) rows
#define NCH  (Ll / 8)         // 256 col-chunks of 8

typedef __attribute__((ext_vector_type(8))) short  short8;  // 8 bf16 = 4 VGPRs
typedef __attribute__((ext_vector_type(4))) float  f32x4;

static __device__ __forceinline__ unsigned short f2bf(float f) {
    union { __hip_bfloat16 h; unsigned short u; } cv;
    cv.h = __float2bfloat16(f);
    return cv.u;
}

// ---- Pass 1: transpose+cvt x (b,c,l) fp32 -> xt[k][b*21+c][8] bf16. ----
// R9 taught: cold reads run at ~2.7 TB/s (row-miss latency ~900cyc x fixed
// ~32-line/CU miss depth) vs ~6 TB/s for row-hit streams, and cross-kernel
// L2 reuse doesn't exist (inter-dispatch L2 flush). x's layout is transposed
// vs the window access at line granularity -> fb's x reads are all row
// misses. Fix it physically: this pass reads x perfectly sequentially
// (row hits); its scattered 16 B writes merge in L2 (xt = 11 MB < 32 MB
// aggregate) and write back as full lines. fb then reads xt contiguously.
__global__ __launch_bounds__(256)
void xpose(const float* __restrict__ x, unsigned short* __restrict__ xt) {
    const int total = NR * NCH;              // 688,128 octets
    for (int t = blockIdx.x * 256 + threadIdx.x; t < total;
         t += gridDim.x * 256) {
        const int row = t >> 8;              // b*21 + c
        const int k   = t & 255;             // col chunk
        const float* src = x + (size_t)row * Ll + k * 8;
        const float4 v0 = *(const float4*)src;
        const float4 v1 = *(const float4*)(src + 4);
        unsigned short* dst = xt + ((size_t)k * NR + row) * 8;
        *(ushort4*)dst =
            make_ushort4(f2bf(v0.x), f2bf(v0.y), f2bf(v0.z), f2bf(v0.w));
        *(ushort4*)(dst + 4) =
            make_ushort4(f2bf(v1.x), f2bf(v1.y), f2bf(v1.z), f2bf(v1.w));
    }
}

// ---- Pass 2: R8 structure on transposed x. ----
// Grid 256 (252 windows + 4 idle), XCD r=bid%8 owns windows [32r,32r+32):
// contiguous 1.4 MB xt region per XCD, within-kernel L2-reused (R4 win).
// Window slab = chunks c0..c0+3 (c0=s/8) = 168 KB aligned contiguous; a
// thread's 21 A-frags span one contiguous 336 B run -> 100% line use, zero
// straddle, row-buffer-friendly. w staged once fp32->bf16 into LDS
// (sequential 43 KB/block); one barrier; 21-MFMA register sweep.
__global__ __launch_bounds__(512)
void fb_mm(const unsigned short* __restrict__ xt, const float* __restrict__ w,
           float* __restrict__ out) {
    __shared__ unsigned short ws[Oo * KP];   // 21.8 KB

    const int bid = blockIdx.x;
    const int j   = (bid & 7) * 32 + (bid >> 3);          // XCD-grouped window
    if (j >= NWw) return;                                  // 4 tail blocks idle
    const int s    = (j < NWw - 1) ? j * Ss : (Ll - 32);  // STARTS[j]
    const int c0   = s >> 3;                               // first col-chunk
    const int tid  = threadIdx.x;
    const int lane = tid & 63;
    const int wv   = tid >> 6;       // 0..7: m-tile id (16 batch rows)
    const int col  = lane & 15;      // MFMA m-row (A) / n-col (B = w-row o)
    const int quad = lane >> 4;      // k-chunk selector

    // batch-issue all 21 A-frags: contiguous 336 B run per thread
    const int m = wv * 16 + col;
    const unsigned short* xrow =
        xt + ((size_t)(c0 + quad) * NR + (size_t)m * Cc) * 8;
    short8 afr[Cc];
#pragma unroll
    for (int c = 0; c < Cc; ++c)
        afr[c] = *(const short8*)(xrow + c * 8);

    // stage weight[j]: 16 x 672 fp32 -> bf16 LDS, [o][k] (B^T)
    {
        const float4* wj4 = (const float4*)(w + (size_t)j * Oo * Kk);
        for (int t = tid; t < Oo * (Kk / 4); t += 512) {   // 2688 float4
            float4 v = wj4[t];
            int o = t / (Kk / 4);                           // Kk/4 = 168
            int r = t - o * (Kk / 4);
            *(ushort4*)&ws[o * KP + r * 4] =
                make_ushort4(f2bf(v.x), f2bf(v.y), f2bf(v.z), f2bf(v.w));
        }
    }
    __syncthreads();

    const unsigned short* wrow = &ws[col * KP + quad * 8];
    f32x4 acc = {0.f, 0.f, 0.f, 0.f};
#pragma unroll
    for (int c = 0; c < Cc; ++c)
        acc = __builtin_amdgcn_mfma_f32_16x16x32_bf16(
            afr[c], *(const short8*)(wrow + c * 32), acc, 0, 0, 0);

    // C/D layout: col = lane&15, row = quad*4 + reg
    const int rbase = wv * 16 + quad * 4;
    float* op = out + (size_t)rbase * NKk + j * 16 + col;
#pragma unroll
    for (int r = 0; r < 4; ++r)
        op[(size_t)r * NKk] = acc[r];
}

extern "C" void kernel_launch(void* const* d_in, const int* in_sizes, int n_in,
                              void* d_out, int out_size, void* d_ws, size_t ws_size,
                              hipStream_t stream) {
    const float* x = (const float*)d_in[0];   // (128, 21, 2048) fp32
    const float* w = (const float*)d_in[1];   // (4032, 672) fp32
    float* out = (float*)d_out;               // (128, 4032) fp32
    unsigned short* xt = (unsigned short*)d_ws;   // 11 MB bf16 transposed x
    xpose<<<dim3(672), dim3(256), 0, stream>>>(x, xt);
    fb_mm<<<dim3(256), dim3(512), 0, stream>>>(xt, w, out);
}